// Round 7
// baseline (99.544 us; speedup 1.0000x reference)
//
#include <hip/hip_runtime.h>
#include <cstdint>

typedef _Float16 f16x8 __attribute__((ext_vector_type(8)));
typedef _Float16 f16x4 __attribute__((ext_vector_type(4)));
typedef float    f32x4 __attribute__((ext_vector_type(4)));

static constexpr int TB = 2;
static constexpr int TT = 2048;
static constexpr int TE = 768;
static constexpr int TH = 12;
static constexpr int TD = 64;
static constexpr int TM = TB * TT;      // 4096 rows (B*T)
static constexpr int TK = TE;           // 768 (K for both GEMMs)
static constexpr int NQKV = 3 * TE;     // 2304

#define SCALE_LOG2E 0.18033688011112042f  /* (1/sqrt(64)) * log2(e) */

// async global->LDS, 16B per lane. LDS dest is wave-uniform base + lane*16.
__device__ __forceinline__ void gload16(const void* g, void* lds) {
  __builtin_amdgcn_global_load_lds(
      (__attribute__((address_space(1))) void*)(uintptr_t)g,
      (__attribute__((address_space(3))) void*)(uint32_t)(uintptr_t)lds, 16, 0, 0);
}

// ---------------------------------------------------------------------------
// f32 -> f16 convert for x, w_qkv, w_final (4 elems/thread)
// ---------------------------------------------------------------------------
__global__ void cvt3(const float* __restrict__ x, const float* __restrict__ wq,
                     const float* __restrict__ wf, _Float16* __restrict__ xh,
                     _Float16* __restrict__ wqh, _Float16* __restrict__ wfh) {
  const int NX = TM * TK / 4, NW = NQKV * TK / 4;
  int i = blockIdx.x * 256 + threadIdx.x;
  const float4* src; _Float16* dst; int j;
  if (i < NX)            { src = (const float4*)x;  dst = xh;  j = i; }
  else if (i < NX + NW)  { src = (const float4*)wq; dst = wqh; j = i - NX; }
  else                   { src = (const float4*)wf; dst = wfh; j = i - NX - NW; }
  float4 v = src[j];
  f16x4 o = {(_Float16)v.x, (_Float16)v.y, (_Float16)v.z, (_Float16)v.w};
  *(f16x4*)&dst[(size_t)j * 4] = o;
}

// ---------------------------------------------------------------------------
// NT GEMM: C[M,N] = A[M,K] * Bw[N,K]^T (+bias). 128x128 tile, BK=64,
// 8 WAVES (512 thr), wave grid 2x4: each wave computes 64x32 out (acc 4x2).
// Waves 0-3 stage the A tile, waves 4-7 the B tile (4 gload16 each).
// Double-buffered K-loop, counted vmcnt(4), raw s_barrier. XCD-chunked grid.
// EPI=0: qkv epilogue (scatter Q scaled, K, V^T s-permuted). EPI=1: f32 out.
// ---------------------------------------------------------------------------
template <int EPI, int NXT>
__global__ __launch_bounds__(512)
void gemm_nt(const _Float16* __restrict__ A, const _Float16* __restrict__ Bw,
             const float* __restrict__ bias,
             _Float16* __restrict__ qb, _Float16* __restrict__ kb,
             _Float16* __restrict__ vtb, float* __restrict__ outp) {
  __shared__ _Float16 As[2][128 * 64];
  __shared__ _Float16 Bs[2][128 * 64];
  const int tid = threadIdx.x;
  const int w = tid >> 6, lane = tid & 63;
  const int lr = lane & 15, lk = lane >> 4;

  const int id = blockIdx.x;
  const int xcd = id & 7, j = id >> 3;
  const int m0 = (xcd * 4 + j / NXT) * 128;  // 4 M-panels per XCD
  const int n0 = (j % NXT) * 128;
  const int wr = w >> 2, wc = w & 3;  // 2x4 wave grid; wave = 64x32 out

  f32x4 acc[4][2] = {};
  const char* Ab = (const char*)(A + (size_t)m0 * TK);
  const char* Bb = (const char*)(Bw + (size_t)n0 * TK);
  const char* Tb = (w < 4) ? Ab : Bb;  // wave-uniform staging split

  // stage one 64-wide K-tile: this wave's 4 KB quarter of A or B
  auto stage = [&](int k0, int buf) {
    char* Ls = (char*)((w < 4) ? As[buf] : Bs[buf]);
#pragma unroll
    for (int c = 0; c < 4; ++c) {
      int g = (w & 3) * 4 + c;  // chunk 0..15 of the 16 KB tile
      int o = g * 1024 + lane * 16;
      int row = o >> 7, ch = (o >> 4) & 7;
      gload16(Tb + (size_t)row * (TK * 2) + k0 * 2 + ((ch ^ (row & 7)) << 4),
              Ls + g * 1024);
    }
  };

  constexpr int NS = TK / 64;  // 12 K-steps
  stage(0, 0);
  for (int ks = 0; ks < NS; ++ks) {
    const int cur = ks & 1;
    if (ks + 1 < NS) {
      stage((ks + 1) * 64, cur ^ 1);  // next tile's 4 loads stay in flight
      asm volatile("s_waitcnt vmcnt(4)" ::: "memory");  // wait only cur's 4
    } else {
      asm volatile("s_waitcnt vmcnt(0)" ::: "memory");
    }
    __builtin_amdgcn_s_barrier();

#pragma unroll
    for (int kc = 0; kc < 2; ++kc) {
      f16x8 af[4], bf[2];
#pragma unroll
      for (int mi = 0; mi < 4; ++mi) {
        int row = wr * 64 + mi * 16 + lr;
        af[mi] =
            *(const f16x8*)&As[cur][row * 64 + (((kc * 4 + lk) ^ (row & 7)) << 3)];
      }
#pragma unroll
      for (int ni = 0; ni < 2; ++ni) {
        int row = wc * 32 + ni * 16 + lr;
        bf[ni] =
            *(const f16x8*)&Bs[cur][row * 64 + (((kc * 4 + lk) ^ (row & 7)) << 3)];
      }
#pragma unroll
      for (int mi = 0; mi < 4; ++mi)
#pragma unroll
        for (int ni = 0; ni < 2; ++ni)
          acc[mi][ni] = __builtin_amdgcn_mfma_f32_16x16x32_f16(af[mi], bf[ni],
                                                               acc[mi][ni], 0, 0, 0);
    }
    __builtin_amdgcn_s_barrier();  // all reads of cur done before restage
  }

  // epilogue: C layout col = lane&15 (N, from 2nd operand), row = (lane>>4)*4+r
#pragma unroll
  for (int mi = 0; mi < 4; ++mi) {
#pragma unroll
    for (int ni = 0; ni < 2; ++ni) {
      const int col = n0 + wc * 32 + ni * 16 + lr;
#pragma unroll
      for (int r = 0; r < 4; ++r) {
        const int row = m0 + wr * 64 + mi * 16 + lk * 4 + r;
        float v = acc[mi][ni][r];
        if (EPI == 0) {
          v += bias[col];
          const int which = (col >= 2 * TE) ? 2 : (col >= TE ? 1 : 0);
          const int e = col - which * TE;
          const int h = e >> 6, d = e & 63;
          const int b = row >> 11, t = row & (TT - 1);
          const size_t hb = (size_t)(b * TH + h);
          if (which == 0)
            qb[(hb * TT + t) * TD + d] = (_Float16)(v * SCALE_LOG2E);
          else if (which == 1)
            kb[(hb * TT + t) * TD + d] = (_Float16)v;
          else {
            // V^T with s-permuted layout within each 64-block
            const int u = t & 63;
            const int up = (u & 0x23) | ((u & 0x0C) << 1) | ((u & 0x10) >> 2);
            const int tp = (t & ~63) | up;
            vtb[(hb * TD + d) * TT + tp] = (_Float16)v;
          }
        } else {
          outp[(size_t)row * TE + col] = v;
        }
      }
    }
  }
}

// ---------------------------------------------------------------------------
// Causal flash attention. Grid 768 = 24 heads x 32 q-tiles, mapped as
//   bh = id % 24, qt = 31 - id/24  -> per-CU work balanced, heavy first.
// 4 waves; wave w owns 16 q-rows. Staging pipeline: gload16 dbuf, counted
// vmcnt, raw s_barrier. SWAPPED QK^T (mfma(K,Q)): lane holds 16 P-values of
// one q-row -> lane-local softmax, P never touches LDS. PV: A = P packed in
// sigma order, B = V^T read as ds_read_b128 (s-permuted global layout).
// T13 defer-max (thr=8, log2 domain).
// ---------------------------------------------------------------------------
__global__ __launch_bounds__(256)
void attn_kernel(const _Float16* __restrict__ qbuf, const _Float16* __restrict__ kbuf,
                 const _Float16* __restrict__ vtbuf, _Float16* __restrict__ ob) {
  __shared__ _Float16 Ks[2][64 * 64], Vs[2][64 * 64];
  const int tid = threadIdx.x, w = tid >> 6, lane = tid & 63;
  const int lr = lane & 15, lk = lane >> 4;

  const int id = blockIdx.x;        // 0..767
  const int bh = id % 24;
  const int qt = 31 - id / 24;      // heavy first, balanced per CU
  const int t0 = qt * 64;

  const size_t hoff = (size_t)bh * (TT * TD);
  const _Float16* q = qbuf + hoff;    // [T][64] (pre-scaled by SCALE*log2e)
  const _Float16* k = kbuf + hoff;    // [T][64]
  const _Float16* vt = vtbuf + hoff;  // [64][T] (s-permuted in 64-blocks)
  const int rb = w * 16;

  f16x8 qf[2];  // B-operand: Q[q=t0+rb+lr][kc*32+lk*8 ..]
#pragma unroll
  for (int kc = 0; kc < 2; ++kc)
    qf[kc] = *(const f16x8*)&q[(size_t)(t0 + rb + lr) * TD + kc * 32 + lk * 8];

  f32x4 of[4] = {};                 // O[q=lk*4+r][d=nd*16+lr]
  float mrun = -1e30f, lrun = 0.f;  // softmax state for q = lane&15 (x4 replicas)

  const int nt = qt + 1;

  auto stage = [&](int st, int buf) {
    const int s0 = st * 64;
#pragma unroll
    for (int c = 0; c < 2; ++c) {
      int o = (w * 2 + c) * 1024 + lane * 16;
      int row = o >> 7, ch = (o >> 4) & 7;
      gload16((const char*)(k + (size_t)s0 * TD) + (size_t)row * 128 +
                  ((ch ^ (row & 7)) << 4),
              (char*)Ks[buf] + (w * 2 + c) * 1024);
      gload16((const char*)(vt + s0) + (size_t)row * (TT * 2) +
                  ((ch ^ (row & 7)) << 4),
              (char*)Vs[buf] + (w * 2 + c) * 1024);
    }
  };

  stage(0, 0);
  for (int st = 0; st < nt; ++st) {
    const int cur = st & 1;
    const int s0 = st * 64;
    if (st + 1 < nt) {
      stage(st + 1, cur ^ 1);  // next tile's 4 loads stay in flight
      asm volatile("s_waitcnt vmcnt(4)" ::: "memory");
    } else {
      asm volatile("s_waitcnt vmcnt(0)" ::: "memory");
    }
    __builtin_amdgcn_s_barrier();

    // S^T tile: sa[ni] = mfma(K, Q): lane holds S[s=s0+ni*16+lk*4+r][q=lr]
    f32x4 sa[4] = {};
    __builtin_amdgcn_s_setprio(1);
#pragma unroll
    for (int kc = 0; kc < 2; ++kc) {
#pragma unroll
      for (int ni = 0; ni < 4; ++ni) {
        int row = ni * 16 + lr;
        f16x8 kf =
            *(const f16x8*)&Ks[cur][row * 64 + (((kc * 4 + lk) ^ (row & 7)) << 3)];
        sa[ni] = __builtin_amdgcn_mfma_f32_16x16x32_f16(kf, qf[kc], sa[ni], 0, 0, 0);
      }
    }
    __builtin_amdgcn_s_setprio(0);

    if (st == nt - 1) {  // diagonal tile: causal mask (s > q)
#pragma unroll
      for (int ni = 0; ni < 4; ++ni)
#pragma unroll
        for (int r = 0; r < 4; ++r)
          if (s0 + ni * 16 + lk * 4 + r > t0 + rb + lr) sa[ni][r] = -1e30f;
    }

    // lane-local row max over 16 values, then reduce over the 4 replica lanes
    float mx;
    {
      float m0_ = fmaxf(fmaxf(sa[0][0], sa[0][1]), fmaxf(sa[0][2], sa[0][3]));
      float m1_ = fmaxf(fmaxf(sa[1][0], sa[1][1]), fmaxf(sa[1][2], sa[1][3]));
      float m2_ = fmaxf(fmaxf(sa[2][0], sa[2][1]), fmaxf(sa[2][2], sa[2][3]));
      float m3_ = fmaxf(fmaxf(sa[3][0], sa[3][1]), fmaxf(sa[3][2], sa[3][3]));
      mx = fmaxf(fmaxf(m0_, m1_), fmaxf(m2_, m3_));
      mx = fmaxf(mx, __shfl_xor(mx, 16));
      mx = fmaxf(mx, __shfl_xor(mx, 32));
    }

    // defer-max: rescale only when the wave sees max growth > 8 (log2 units)
    if (__any(mx > mrun + 8.0f)) {
      float mn = fmaxf(mrun, mx);
      float al = __builtin_amdgcn_exp2f(mrun - mn);
      mrun = mn;
      lrun *= al;
      float al4[4];
#pragma unroll
      for (int r = 0; r < 4; ++r) al4[r] = __shfl(al, lk * 4 + r);
#pragma unroll
      for (int nd = 0; nd < 4; ++nd)
#pragma unroll
        for (int r = 0; r < 4; ++r) of[nd][r] *= al4[r];
    }

    // P = exp2(sa - mrun); pack PV A-fragments: pa[kc] slot 4*hi+m holds
    // P[q=lr][s = 32kc + 16hi + 4lk + m]  (hi = ni&1, m = r)
    f16x8 pa[2];
    float rs;
    {
      float rn[4];
#pragma unroll
      for (int ni = 0; ni < 4; ++ni) {
        float p0 = __builtin_amdgcn_exp2f(sa[ni][0] - mrun);
        float p1 = __builtin_amdgcn_exp2f(sa[ni][1] - mrun);
        float p2 = __builtin_amdgcn_exp2f(sa[ni][2] - mrun);
        float p3 = __builtin_amdgcn_exp2f(sa[ni][3] - mrun);
        rn[ni] = (p0 + p1) + (p2 + p3);
        pa[ni >> 1][(ni & 1) * 4 + 0] = (_Float16)p0;
        pa[ni >> 1][(ni & 1) * 4 + 1] = (_Float16)p1;
        pa[ni >> 1][(ni & 1) * 4 + 2] = (_Float16)p2;
        pa[ni >> 1][(ni & 1) * 4 + 3] = (_Float16)p3;
      }
      rs = (rn[0] + rn[1]) + (rn[2] + rn[3]);
      rs += __shfl_xor(rs, 16);
      rs += __shfl_xor(rs, 32);
    }
    lrun += rs;

    // O += P V: B-fragment is one ds_read_b128 (s-permuted layout), chunk =
    // kc*4+lk -> identical pattern to the K read (conflict-free).
    __builtin_amdgcn_s_setprio(1);
#pragma unroll
    for (int kc = 0; kc < 2; ++kc) {
#pragma unroll
      for (int nd = 0; nd < 4; ++nd) {
        int row = nd * 16 + lr;
        f16x8 vv =
            *(const f16x8*)&Vs[cur][row * 64 + (((kc * 4 + lk) ^ (row & 7)) << 3)];
        of[nd] = __builtin_amdgcn_mfma_f32_16x16x32_f16(pa[kc], vv, of[nd], 0, 0, 0);
      }
    }
    __builtin_amdgcn_s_setprio(0);
    __builtin_amdgcn_s_barrier();  // protect cur buffer before restage
  }

  // epilogue: need lrun for q = lk*4+r (owner lane lr = q)
  float linv[4];
#pragma unroll
  for (int r = 0; r < 4; ++r) linv[r] = __shfl(lrun, lk * 4 + r);
  const int b = bh / TH, h = bh - b * TH;
#pragma unroll
  for (int nd = 0; nd < 4; ++nd) {
#pragma unroll
    for (int r = 0; r < 4; ++r) {
      int tg = t0 + rb + lk * 4 + r;
      int d = nd * 16 + lr;
      ob[(size_t)(b * TT + tg) * TE + h * TD + d] = (_Float16)(of[nd][r] / linv[r]);
    }
  }
}

// ---------------------------------------------------------------------------
extern "C" void kernel_launch(void* const* d_in, const int* in_sizes, int n_in,
                              void* d_out, int out_size, void* d_ws, size_t ws_size,
                              hipStream_t stream) {
  const float* x    = (const float*)d_in[0];
  const float* wqkv = (const float*)d_in[1];
  const float* bqkv = (const float*)d_in[2];
  const float* wfin = (const float*)d_in[3];
  float* out = (float*)d_out;

  _Float16* xh  = (_Float16*)d_ws;          // [4096][768]
  _Float16* wqh = xh + (size_t)TM * TK;     // [2304][768]
  _Float16* wfh = wqh + (size_t)NQKV * TK;  // [768][768]
  _Float16* qb  = wfh + (size_t)TE * TE;    // [B,H,T,D] (pre-scaled)
  _Float16* kb  = qb + (size_t)TM * TE;     // [B,H,T,D]
  _Float16* vtb = kb + (size_t)TM * TE;     // [B,H,D,T] (s-permuted)
  _Float16* ob  = vtb + (size_t)TM * TE;    // [4096][768] attn output

  cvt3<<<5376, 256, 0, stream>>>(x, wqkv, wfin, xh, wqh, wfh);
  gemm_nt<0, NQKV / 128><<<(NQKV / 128) * (TM / 128), 512, 0, stream>>>(
      xh, wqh, bqkv, qb, kb, vtb, nullptr);
  attn_kernel<<<dim3(TT / 64 * TB * TH), 256, 0, stream>>>(qb, kb, vtb, ob);
  gemm_nt<1, TE / 128><<<(TE / 128) * (TM / 128), 512, 0, stream>>>(
      ob, wfh, nullptr, nullptr, nullptr, nullptr, out);
}

// Round 8
// 86.707 us; speedup vs baseline: 1.1480x; 1.1480x over previous
//
#include <hip/hip_runtime.h>
#include <cstdint>

typedef _Float16 f16x8 __attribute__((ext_vector_type(8)));
typedef _Float16 f16x4 __attribute__((ext_vector_type(4)));
typedef float    f32x4 __attribute__((ext_vector_type(4)));

static constexpr int TB = 2;
static constexpr int TT = 2048;
static constexpr int TE = 768;
static constexpr int TH = 12;
static constexpr int TD = 64;
static constexpr int TM = TB * TT;      // 4096 rows (B*T)
static constexpr int TK = TE;           // 768 (K for both GEMMs)
static constexpr int NQKV = 3 * TE;     // 2304

#define SCALE_LOG2E 0.18033688011112042f  /* (1/sqrt(64)) * log2(e) */

// async global->LDS, 16B per lane. LDS dest is wave-uniform base + lane*16.
__device__ __forceinline__ void gload16(const void* g, void* lds) {
  __builtin_amdgcn_global_load_lds(
      (__attribute__((address_space(1))) void*)(uintptr_t)g,
      (__attribute__((address_space(3))) void*)(uint32_t)(uintptr_t)lds, 16, 0, 0);
}

// ---------------------------------------------------------------------------
// f32 -> f16 convert for x, w_qkv, w_final (4 elems/thread)
// ---------------------------------------------------------------------------
__global__ void cvt3(const float* __restrict__ x, const float* __restrict__ wq,
                     const float* __restrict__ wf, _Float16* __restrict__ xh,
                     _Float16* __restrict__ wqh, _Float16* __restrict__ wfh) {
  const int NX = TM * TK / 4, NW = NQKV * TK / 4;
  int i = blockIdx.x * 256 + threadIdx.x;
  const float4* src; _Float16* dst; int j;
  if (i < NX)            { src = (const float4*)x;  dst = xh;  j = i; }
  else if (i < NX + NW)  { src = (const float4*)wq; dst = wqh; j = i - NX; }
  else                   { src = (const float4*)wf; dst = wfh; j = i - NX - NW; }
  float4 v = src[j];
  f16x4 o = {(_Float16)v.x, (_Float16)v.y, (_Float16)v.z, (_Float16)v.w};
  *(f16x4*)&dst[(size_t)j * 4] = o;
}

// ---------------------------------------------------------------------------
// NT GEMM: C[M,N] = A[M,K] * Bw[N,K]^T (+bias). 128x128 tile, BK=64,
// 8 waves (512 thr), wave grid 2x4 (64x32 out each). Waves 0-3 stage A,
// 4-7 stage B. Dbuf K-loop, counted vmcnt(4), raw s_barrier. XCD-chunked.
// EPI=0 epilogue scatters Q (pre-scaled) in [B,H,T,D], and K,V in
// MFMA-FRAGMENT-NATIVE layouts so attn can load fragments coalesced:
//   K': f16 idx = ((hb*128 + (t>>4))*8 + (d>>3))*16 + (t&15))*8 + (d&7)
//   V': f16 idx = (((((hb*32 + (t>>6))*4 + (d>>4))*2 + kc)*4 + lk)*16
//                  + (d&15))*8 + hi*4 + m,
//       kc=(t>>5)&1, hi=(t>>4)&1, lk=(t>>2)&3, m=t&3
// EPI=1: plain f32 out.
// ---------------------------------------------------------------------------
template <int EPI, int NXT>
__global__ __launch_bounds__(512)
void gemm_nt(const _Float16* __restrict__ A, const _Float16* __restrict__ Bw,
             const float* __restrict__ bias,
             _Float16* __restrict__ qb, _Float16* __restrict__ kb,
             _Float16* __restrict__ vtb, float* __restrict__ outp) {
  __shared__ _Float16 As[2][128 * 64];
  __shared__ _Float16 Bs[2][128 * 64];
  const int tid = threadIdx.x;
  const int w = tid >> 6, lane = tid & 63;
  const int lr = lane & 15, lk = lane >> 4;

  const int id = blockIdx.x;
  const int xcd = id & 7, j = id >> 3;
  const int m0 = (xcd * 4 + j / NXT) * 128;  // 4 M-panels per XCD
  const int n0 = (j % NXT) * 128;
  const int wr = w >> 2, wc = w & 3;  // 2x4 wave grid; wave = 64x32 out

  f32x4 acc[4][2] = {};
  const char* Ab = (const char*)(A + (size_t)m0 * TK);
  const char* Bb = (const char*)(Bw + (size_t)n0 * TK);
  const char* Tb = (w < 4) ? Ab : Bb;  // wave-uniform staging split

  auto stage = [&](int k0, int buf) {
    char* Ls = (char*)((w < 4) ? As[buf] : Bs[buf]);
#pragma unroll
    for (int c = 0; c < 4; ++c) {
      int g = (w & 3) * 4 + c;  // chunk 0..15 of the 16 KB tile
      int o = g * 1024 + lane * 16;
      int row = o >> 7, ch = (o >> 4) & 7;
      gload16(Tb + (size_t)row * (TK * 2) + k0 * 2 + ((ch ^ (row & 7)) << 4),
              Ls + g * 1024);
    }
  };

  constexpr int NS = TK / 64;  // 12 K-steps
  stage(0, 0);
  for (int ks = 0; ks < NS; ++ks) {
    const int cur = ks & 1;
    if (ks + 1 < NS) {
      stage((ks + 1) * 64, cur ^ 1);  // next tile's 4 loads stay in flight
      asm volatile("s_waitcnt vmcnt(4)" ::: "memory");  // wait only cur's 4
    } else {
      asm volatile("s_waitcnt vmcnt(0)" ::: "memory");
    }
    __builtin_amdgcn_s_barrier();

#pragma unroll
    for (int kc = 0; kc < 2; ++kc) {
      f16x8 af[4], bf[2];
#pragma unroll
      for (int mi = 0; mi < 4; ++mi) {
        int row = wr * 64 + mi * 16 + lr;
        af[mi] =
            *(const f16x8*)&As[cur][row * 64 + (((kc * 4 + lk) ^ (row & 7)) << 3)];
      }
#pragma unroll
      for (int ni = 0; ni < 2; ++ni) {
        int row = wc * 32 + ni * 16 + lr;
        bf[ni] =
            *(const f16x8*)&Bs[cur][row * 64 + (((kc * 4 + lk) ^ (row & 7)) << 3)];
      }
#pragma unroll
      for (int mi = 0; mi < 4; ++mi)
#pragma unroll
        for (int ni = 0; ni < 2; ++ni)
          acc[mi][ni] = __builtin_amdgcn_mfma_f32_16x16x32_f16(af[mi], bf[ni],
                                                               acc[mi][ni], 0, 0, 0);
    }
    __builtin_amdgcn_s_barrier();  // all reads of cur done before restage
  }

  // epilogue: C layout col = lane&15 (N), row = (lane>>4)*4 + r
#pragma unroll
  for (int mi = 0; mi < 4; ++mi) {
#pragma unroll
    for (int ni = 0; ni < 2; ++ni) {
      const int col = n0 + wc * 32 + ni * 16 + lr;
#pragma unroll
      for (int r = 0; r < 4; ++r) {
        const int row = m0 + wr * 64 + mi * 16 + lk * 4 + r;
        float v = acc[mi][ni][r];
        if (EPI == 0) {
          v += bias[col];
          const int which = (col >= 2 * TE) ? 2 : (col >= TE ? 1 : 0);
          const int e = col - which * TE;
          const int h = e >> 6, d = e & 63;
          const int b = row >> 11, t = row & (TT - 1);
          const size_t hb = (size_t)(b * TH + h);
          if (which == 0) {
            qb[(hb * TT + t) * TD + d] = (_Float16)(v * SCALE_LOG2E);
          } else if (which == 1) {
            // K' fragment-native
            kb[((((hb * 128 + (t >> 4)) * 8 + (d >> 3)) * 16 + (t & 15)) * 8) +
               (d & 7)] = (_Float16)v;
          } else {
            // V' fragment-native
            const int kc = (t >> 5) & 1, hi = (t >> 4) & 1;
            const int lkv = (t >> 2) & 3, m = t & 3;
            vtb[((((((hb * 32 + (t >> 6)) * 4 + (d >> 4)) * 2 + kc) * 4 + lkv) *
                      16 +
                  (d & 15)) *
                 8) +
                (hi * 4 + m)] = (_Float16)v;
          }
        } else {
          outp[(size_t)row * TE + col] = v;
        }
      }
    }
  }
}

// ---------------------------------------------------------------------------
// Causal flash attention, BARRIER-FREE, NO LDS. Grid 768 = 24 heads x 32
// q-tiles (bh = id%24 pins each head to one XCD; qt = 31 - id/24, heavy
// first). 4 independent waves/block; wave w owns 16 q-rows. K and V are in
// fragment-native global layouts -> every fragment is a contiguous 1KB wave
// load straight to VGPR (lane addr = base + lane*16B). Software pipeline:
// kfA/kfB register double-buffer, K prefetched 2 tiles ahead, V issued at
// phase start (1 phase of cover); compiler derives counted vmcnt waits.
// 4 waves of a block share tiles -> L1 serves the 4x reuse.
// SWAPPED QK^T (mfma(K,Q)): lane-local softmax; P never leaves registers.
// T13 defer-max (thr=8, log2 domain).
// ---------------------------------------------------------------------------
__global__ __launch_bounds__(256)
void attn_kernel(const _Float16* __restrict__ qbuf, const _Float16* __restrict__ kbuf,
                 const _Float16* __restrict__ vtbuf, _Float16* __restrict__ ob) {
  const int tid = threadIdx.x, w = tid >> 6, lane = tid & 63;
  const int lr = lane & 15, lk = lane >> 4;

  const int id = blockIdx.x;        // 0..767
  const int bh = id % 24;
  const int qt = 31 - id / 24;      // heavy first, balanced per CU
  const int t0 = qt * 64;
  const int nt = qt + 1, ntm1 = qt;

  const _Float16* q = qbuf + (size_t)bh * (TT * TD);  // [T][64], pre-scaled
  // per-lane fragment base: + lk*256 + lr*16 bytes; tile stride 8192B;
  // fragment imm offset = ni(nd)*2048 + kc*1024
  const char* kbase =
      (const char*)(kbuf + (size_t)bh * (TT * TD)) + lk * 256 + lr * 16;
  const char* vbase =
      (const char*)(vtbuf + (size_t)bh * (TT * TD)) + lk * 256 + lr * 16;

  f16x8 qf[2];  // B-operand: Q[q=t0+w*16+lr][kc*32+lk*8 ..]
#pragma unroll
  for (int kc = 0; kc < 2; ++kc)
    qf[kc] = *(const f16x8*)&q[(size_t)(t0 + w * 16 + lr) * TD + kc * 32 + lk * 8];

  f32x4 of[4] = {};                 // O[q=lk*4+r][d=nd*16+lr]
  float mrun = -1e30f, lrun = 0.f;  // softmax state for q = lane&15 (x4 replicas)

  f16x8 kfA[2][4], kfB[2][4], vf[2][4];

  // prologue: K(0) -> kfA, K(1) -> kfB (clamped)
#pragma unroll
  for (int kc = 0; kc < 2; ++kc)
#pragma unroll
    for (int ni = 0; ni < 4; ++ni)
      kfA[kc][ni] = *(const f16x8*)(kbase + ni * 2048 + kc * 1024);
  {
    const char* k1 = kbase + (size_t)(nt > 1 ? 1 : 0) * 8192;
#pragma unroll
    for (int kc = 0; kc < 2; ++kc)
#pragma unroll
      for (int ni = 0; ni < 4; ++ni)
        kfB[kc][ni] = *(const f16x8*)(k1 + ni * 2048 + kc * 1024);
  }

  auto phase = [&](f16x8 (&kf)[2][4], int st) {
    // issue V(st) loads (consumed by PV below; cover = QK^T + softmax)
    const char* vt = vbase + (size_t)st * 8192;
#pragma unroll
    for (int kc = 0; kc < 2; ++kc)
#pragma unroll
      for (int nd = 0; nd < 4; ++nd)
        vf[kc][nd] = *(const f16x8*)(vt + nd * 2048 + kc * 1024);

    // S^T: sa[ni] = mfma(K, Q): lane holds S[s=st*64+ni*16+lk*4+r][q=lr]
    f32x4 sa[4] = {};
    __builtin_amdgcn_s_setprio(1);
#pragma unroll
    for (int kc = 0; kc < 2; ++kc)
#pragma unroll
      for (int ni = 0; ni < 4; ++ni)
        sa[ni] =
            __builtin_amdgcn_mfma_f32_16x16x32_f16(kf[kc][ni], qf[kc], sa[ni], 0, 0, 0);
    __builtin_amdgcn_s_setprio(0);

    // prefetch K(st+2) into the buffer just consumed (clamped; 2-phase cover)
    {
      const int stp = (st + 2 <= ntm1) ? st + 2 : ntm1;
      const char* kt = kbase + (size_t)stp * 8192;
#pragma unroll
      for (int kc = 0; kc < 2; ++kc)
#pragma unroll
        for (int ni = 0; ni < 4; ++ni)
          kf[kc][ni] = *(const f16x8*)(kt + ni * 2048 + kc * 1024);
    }

    if (st == ntm1) {  // diagonal tile: causal mask (s > q)
      const int s0 = st * 64;
#pragma unroll
      for (int ni = 0; ni < 4; ++ni)
#pragma unroll
        for (int r = 0; r < 4; ++r)
          if (s0 + ni * 16 + lk * 4 + r > t0 + w * 16 + lr) sa[ni][r] = -1e30f;
    }

    // lane-local row max, then reduce over the 4 replica lanes
    float mx;
    {
      float m0_ = fmaxf(fmaxf(sa[0][0], sa[0][1]), fmaxf(sa[0][2], sa[0][3]));
      float m1_ = fmaxf(fmaxf(sa[1][0], sa[1][1]), fmaxf(sa[1][2], sa[1][3]));
      float m2_ = fmaxf(fmaxf(sa[2][0], sa[2][1]), fmaxf(sa[2][2], sa[2][3]));
      float m3_ = fmaxf(fmaxf(sa[3][0], sa[3][1]), fmaxf(sa[3][2], sa[3][3]));
      mx = fmaxf(fmaxf(m0_, m1_), fmaxf(m2_, m3_));
      mx = fmaxf(mx, __shfl_xor(mx, 16));
      mx = fmaxf(mx, __shfl_xor(mx, 32));
    }

    // defer-max: rescale only when the wave sees max growth > 8 (log2 units)
    if (__any(mx > mrun + 8.0f)) {
      float mn = fmaxf(mrun, mx);
      float al = __builtin_amdgcn_exp2f(mrun - mn);
      mrun = mn;
      lrun *= al;
      float al4[4];
#pragma unroll
      for (int r = 0; r < 4; ++r) al4[r] = __shfl(al, lk * 4 + r);
#pragma unroll
      for (int nd = 0; nd < 4; ++nd)
#pragma unroll
        for (int r = 0; r < 4; ++r) of[nd][r] *= al4[r];
    }

    // P = exp2(sa - mrun); pack PV A-fragments: pa[kc] slot 4*hi+m holds
    // P[q=lr][s = 32kc + 16hi + 4lk + m]  (hi = ni&1, m = r)
    f16x8 pa[2];
    float rs;
    {
      float rn[4];
#pragma unroll
      for (int ni = 0; ni < 4; ++ni) {
        float p0 = __builtin_amdgcn_exp2f(sa[ni][0] - mrun);
        float p1 = __builtin_amdgcn_exp2f(sa[ni][1] - mrun);
        float p2 = __builtin_amdgcn_exp2f(sa[ni][2] - mrun);
        float p3 = __builtin_amdgcn_exp2f(sa[ni][3] - mrun);
        rn[ni] = (p0 + p1) + (p2 + p3);
        pa[ni >> 1][(ni & 1) * 4 + 0] = (_Float16)p0;
        pa[ni >> 1][(ni & 1) * 4 + 1] = (_Float16)p1;
        pa[ni >> 1][(ni & 1) * 4 + 2] = (_Float16)p2;
        pa[ni >> 1][(ni & 1) * 4 + 3] = (_Float16)p3;
      }
      rs = (rn[0] + rn[1]) + (rn[2] + rn[3]);
      rs += __shfl_xor(rs, 16);
      rs += __shfl_xor(rs, 32);
    }
    lrun += rs;

    // O += P V (B-fragment = vf, slot j = hi*4+m matches pa by construction)
    __builtin_amdgcn_s_setprio(1);
#pragma unroll
    for (int kc = 0; kc < 2; ++kc)
#pragma unroll
      for (int nd = 0; nd < 4; ++nd)
        of[nd] =
            __builtin_amdgcn_mfma_f32_16x16x32_f16(pa[kc], vf[kc][nd], of[nd], 0, 0, 0);
    __builtin_amdgcn_s_setprio(0);
  };

  int st = 0;
  while (st + 1 < nt) {
    phase(kfA, st);
    phase(kfB, st + 1);
    st += 2;
  }
  if (st < nt) phase(kfA, st);

  // epilogue: need lrun for q = lk*4+r (owner lane lr = q)
  float linv[4];
#pragma unroll
  for (int r = 0; r < 4; ++r) linv[r] = __shfl(lrun, lk * 4 + r);
  const int b = bh / TH, h = bh - b * TH;
#pragma unroll
  for (int nd = 0; nd < 4; ++nd) {
#pragma unroll
    for (int r = 0; r < 4; ++r) {
      int tg = t0 + w * 16 + lk * 4 + r;
      int d = nd * 16 + lr;
      ob[(size_t)(b * TT + tg) * TE + h * TD + d] = (_Float16)(of[nd][r] / linv[r]);
    }
  }
}

// ---------------------------------------------------------------------------
extern "C" void kernel_launch(void* const* d_in, const int* in_sizes, int n_in,
                              void* d_out, int out_size, void* d_ws, size_t ws_size,
                              hipStream_t stream) {
  const float* x    = (const float*)d_in[0];
  const float* wqkv = (const float*)d_in[1];
  const float* bqkv = (const float*)d_in[2];
  const float* wfin = (const float*)d_in[3];
  float* out = (float*)d_out;

  _Float16* xh  = (_Float16*)d_ws;          // [4096][768]
  _Float16* wqh = xh + (size_t)TM * TK;     // [2304][768]
  _Float16* wfh = wqh + (size_t)NQKV * TK;  // [768][768]
  _Float16* qb  = wfh + (size_t)TE * TE;    // [B,H,T,D] (pre-scaled)
  _Float16* kb  = qb + (size_t)TM * TE;     // K' fragment-native
  _Float16* vtb = kb + (size_t)TM * TE;     // V' fragment-native
  _Float16* ob  = vtb + (size_t)TM * TE;    // [4096][768] attn output

  cvt3<<<5376, 256, 0, stream>>>(x, wqkv, wfin, xh, wqh, wfh);
  gemm_nt<0, NQKV / 128><<<(NQKV / 128) * (TM / 128), 512, 0, stream>>>(
      xh, wqh, bqkv, qb, kb, vtb, nullptr);
  attn_kernel<<<dim3(TT / 64 * TB * TH), 256, 0, stream>>>(qb, kb, vtb, ob);
  gemm_nt<1, TE / 128><<<(TE / 128) * (TM / 128), 512, 0, stream>>>(
      ob, wfh, nullptr, nullptr, nullptr, nullptr, out);
}